// Round 15
// baseline (213.317 us; speedup 1.0000x reference)
//
#include <hip/hip_runtime.h>
#include <hip/hip_bf16.h>
#include <math.h>

// Problem constants
#define BB 2
#define SS 2048
#define DD 2048
#define HH 16
#define GG 4
#define HDIM 128
#define DKV (GG * HDIM)      // 512
#define MS (BB * SS)         // 4096 rows
#define QKVS 3072            // fused QKV row stride (2048 Q + 512 K + 512 V)

typedef __attribute__((ext_vector_type(8))) short bf16x8;
typedef __attribute__((ext_vector_type(4))) float f32x4;
typedef __attribute__((ext_vector_type(4))) unsigned int u32x4;

__device__ __forceinline__ ushort f2bf(float x) {
    __hip_bfloat16 b = __float2bfloat16(x);
    return *(ushort*)&b;
}
__device__ __forceinline__ float bf2f(ushort u) {
    __hip_bfloat16 b;
    *(ushort*)&b = u;
    return __bfloat162float(b);
}

#define GLOAD_LDS(src, dst)                                                        \
    __builtin_amdgcn_global_load_lds(                                              \
        (const __attribute__((address_space(1))) unsigned int*)(src),              \
        (__attribute__((address_space(3))) unsigned int*)(dst), 16, 0, 0)

#define WAITV(n) asm volatile("s_waitcnt vmcnt(" #n ")" ::: "memory")

// ---------------- fp32 -> bf16 cast, 8 elems/thread ----------------
__global__ void cast_bf16(const float* __restrict__ X, ushort* __restrict__ O, int total8) {
    int idx = blockIdx.x * blockDim.x + threadIdx.x;
    if (idx >= total8) return;
    const float4* p = (const float4*)X + (size_t)idx * 2;
    float4 a = p[0], b = p[1];
    float v[8] = {a.x, a.y, a.z, a.w, b.x, b.y, b.z, b.w};
    ushort r[8];
#pragma unroll
    for (int j = 0; j < 8; ++j) r[j] = f2bf(v[j]);
    *((u32x4*)O + idx) = *(u32x4*)r;
}

// ------- merged weight transpose+cast: z=0 Wq, z=1 Wk, z=2 Wv -> WqkvT -------
__global__ __launch_bounds__(256) void transpose_cast3(const float* __restrict__ Wq,
                                                       const float* __restrict__ Wk,
                                                       const float* __restrict__ Wv,
                                                       ushort* __restrict__ WqkvT) {
    __shared__ ushort tile[32][33];
    const int z = blockIdx.z;
    if (z > 0 && blockIdx.x >= DKV / 32) return;
    const float* W = (z == 0) ? Wq : (z == 1) ? Wk : Wv;
    ushort* WT = WqkvT + ((z == 0) ? (size_t)0 : (z == 1) ? (size_t)DD * DD
                                                          : (size_t)(DD + DKV) * DD);
    const int N = (z == 0) ? DD : DKV;
    const int tx = threadIdx.x & 31, ty = threadIdx.x >> 5;  // 32 x 8
    const int n0 = blockIdx.x * 32, k0 = blockIdx.y * 32;
#pragma unroll
    for (int i = 0; i < 4; ++i)
        tile[ty + i * 8][tx] = f2bf(W[(size_t)(k0 + ty + i * 8) * N + n0 + tx]);
    __syncthreads();
#pragma unroll
    for (int i = 0; i < 4; ++i)
        WT[(size_t)(n0 + ty + i * 8) * DD + k0 + tx] = tile[tx][ty + i * 8];
}

// ---------------- transpose + cast (single): WT[n*K+k] = bf16(W[k*N+n]) ------
__global__ __launch_bounds__(256) void transpose_cast(const float* __restrict__ W,
                                                      ushort* __restrict__ WT,
                                                      int K, int N) {
    __shared__ ushort tile[32][33];
    const int tx = threadIdx.x & 31, ty = threadIdx.x >> 5;
    const int n0 = blockIdx.x * 32, k0 = blockIdx.y * 32;
#pragma unroll
    for (int i = 0; i < 4; ++i)
        tile[ty + i * 8][tx] = f2bf(W[(size_t)(k0 + ty + i * 8) * N + n0 + tx]);
    __syncthreads();
#pragma unroll
    for (int i = 0; i < 4; ++i)
        WT[(size_t)(n0 + ty + i * 8) * K + k0 + tx] = tile[tx][ty + i * 8];
}

// ---- per-batch V transpose from fused QKV, with PV-slot column permutation ----
// tau: kv = 32a+16m+4w+r  ->  pos = 32a+8w+4m+r
__global__ __launch_bounds__(256) void transpose_v(const ushort* __restrict__ QKV,
                                                   ushort* __restrict__ VT) {
    __shared__ ushort tile[32][33];
    const int tx = threadIdx.x & 31, ty = threadIdx.x >> 5;
    const int d0 = blockIdx.x * 32;
    const int k0 = blockIdx.y * 32;
    const int b = blockIdx.z;
#pragma unroll
    for (int i = 0; i < 4; ++i)
        tile[ty + i * 8][tx] =
            QKV[(size_t)(b * SS + k0 + ty + i * 8) * QKVS + 2560 + d0 + tx];
    __syncthreads();
    const int posl = ((tx & 12) << 1) | ((tx & 16) >> 2) | (tx & 3);
#pragma unroll
    for (int i = 0; i < 4; ++i)
        VT[((size_t)b * DKV + d0 + ty + i * 8) * SS + k0 + posl] = tile[tx][ty + i * 8];
}

// ---------------- bf16 MFMA GEMM v3: BM=128, ring-3, 2 blocks/CU ---------------
template <int BN, bool OUT_BF16>
__global__ __launch_bounds__(512) void gemm8(const ushort* __restrict__ A,
                                             const ushort* __restrict__ BT,
                                             void* __restrict__ Cout,
                                             int M, int N, int K) {
    constexpr int ABUF = 128 * 32;
    constexpr int BBUF = BN * 32;
    constexpr int NWC = BN / 64;
    constexpr int NWM = 8 / NWC;
    constexpr int ROWS = 128 / NWM;
    constexpr int MFR = ROWS / 16;
    __shared__ ushort As[3 * ABUF];
    __shared__ ushort Bs[3 * BBUF];

    const int t = threadIdx.x;
    const int w = t >> 6, l = t & 63;
    const int lm = l & 15, lw = l >> 4;
    const int wr = w / NWC, wc = w % NWC;
    const int nx = gridDim.x;
    const int bid = blockIdx.y * nx + blockIdx.x;
    const int cpx = (nx * gridDim.y) >> 3;
    const int swb = (bid & 7) * cpx + (bid >> 3);
    const int bm = (swb / nx) * 128, bn = (swb % nx) * BN;

    const int NT = K >> 5;
    const int swzc = (lw ^ ((lm >> 1) & 3)) * 8;

    const int ar0 = t >> 2, ac0 = (t & 3) ^ ((ar0 >> 1) & 3);
    const ushort* a0 = A + (size_t)(bm + ar0) * K + ac0 * 8;
    const int br0 = t >> 2, bc0 = (t & 3) ^ ((br0 >> 1) & 3);
    const ushort* b0 = BT + (size_t)(bn + br0) * K + bc0 * 8;
    const int br1 = (t + 512) >> 2, bc1 = ((t + 512) & 3) ^ ((br1 >> 1) & 3);
    const ushort* b1 = BT + (size_t)(bn + br1) * K + bc1 * 8;  // BN==256 only

    auto STAGE = [&](int slot) {
        GLOAD_LDS(a0, &As[slot * ABUF + t * 8]);
        a0 += 32;
        GLOAD_LDS(b0, &Bs[slot * BBUF + t * 8]);
        b0 += 32;
        if constexpr (BN == 256) {
            GLOAD_LDS(b1, &Bs[slot * BBUF + (t + 512) * 8]);
            b1 += 32;
        }
    };

    f32x4 acc[MFR][4];
#pragma unroll
    for (int m = 0; m < MFR; ++m)
#pragma unroll
        for (int n = 0; n < 4; ++n) acc[m][n] = (f32x4){0.f, 0.f, 0.f, 0.f};

    STAGE(0);
    STAGE(1);
    int cs = 0, ps = 2;

#pragma unroll 1
    for (int kt = 0; kt < NT; ++kt) {
        if (kt + 1 < NT) {
            if constexpr (BN == 256) WAITV(3); else WAITV(2);
        } else {
            WAITV(0);
        }
        __builtin_amdgcn_s_barrier();
        if (kt + 2 < NT) STAGE(ps);

        const ushort* Ab = &As[cs * ABUF];
        const ushort* Bb = &Bs[cs * BBUF];
        bf16x8 bfr[4], af[MFR];
#pragma unroll
        for (int n = 0; n < 4; ++n)
            bfr[n] = *(const bf16x8*)&Bb[(wc * 64 + n * 16 + lm) * 32 + swzc];
#pragma unroll
        for (int i = 0; i < MFR; ++i)
            af[i] = *(const bf16x8*)&Ab[(wr * ROWS + i * 16 + lm) * 32 + swzc];
        __builtin_amdgcn_s_setprio(1);
#pragma unroll
        for (int i = 0; i < MFR; ++i)
#pragma unroll
            for (int n = 0; n < 4; ++n)
                acc[i][n] = __builtin_amdgcn_mfma_f32_16x16x32_bf16(af[i], bfr[n], acc[i][n], 0, 0, 0);
        __builtin_amdgcn_s_setprio(0);

        cs = (cs == 2) ? 0 : cs + 1;
        ps = (ps == 2) ? 0 : ps + 1;
    }

#pragma unroll
    for (int m = 0; m < MFR; ++m)
#pragma unroll
        for (int n = 0; n < 4; ++n)
#pragma unroll
            for (int r = 0; r < 4; ++r) {
                int row = bm + wr * ROWS + m * 16 + lw * 4 + r;
                int col = bn + wc * 64 + n * 16 + lm;
                if (OUT_BF16)
                    ((ushort*)Cout)[(size_t)row * N + col] = f2bf(acc[m][n][r]);
                else
                    ((float*)Cout)[(size_t)row * N + col] = acc[m][n][r];
            }
}

// ------- RoPE in-place on bf16, fused Q+K in one launch (heads 0..19) -------
__global__ void rope_bf16(ushort* __restrict__ X, int total) {
    int idx = blockIdx.x * blockDim.x + threadIdx.x;
    if (idx >= total) return;
    int i = idx & 63;
    int hh = (idx >> 6) % 20;
    int row = idx / (64 * 20);
    int s = row & (SS - 1);
    int colOff = (hh < 16) ? hh * HDIM : 2048 + (hh - 16) * HDIM;
    float inv = exp2f((float)i * -0.2076205059304601f);  // 10000^(-2i/128)
    float ang = (float)s * inv;
    float c, sn;
    __sincosf(ang, &sn, &c);
    size_t base = (size_t)row * QKVS + colOff + i;
    float x1 = bf2f(X[base]), x2 = bf2f(X[base + 64]);
    X[base] = f2bf(x1 * c - x2 * sn);
    X[base + 64] = f2bf(x2 * c + x1 * sn);
}

// ---------------- MFMA flash attention v13: v9 + 2-deep P pipeline -----------
// 256 blocks x 8 waves, q-tile 128, paired phases {xq, 15-xq}. K double-buffered,
// V in 3-slot ring (80 KB LDS). Tile body reordered: QK^T(t) -> PV(t-1) ->
// softmax(t)->pa(t). PV(t-1) lands in acc BEFORE tile-t's rescale (preserves
// online-softmax algebra); exp2/cvt chain moves off the MFMA critical path.
#define SCL 0.08838834764831845f          // 1/sqrt(128)
#define CEXP 0.1275296340545927f          // SCL * log2(e)
#define THRRAW 90.50966799187809f         // 8 / SCL

__global__ __launch_bounds__(512) void attn_mfma(const ushort* __restrict__ QKV,
                                                 const ushort* __restrict__ VT,
                                                 ushort* __restrict__ Ctx) {
    __shared__ ushort Ks[2][64 * 128];  // 32 KB
    __shared__ ushort Vs[3][128 * 64];  // 48 KB
    const int t = threadIdx.x;          // 0..511
    const int w = t >> 6;               // wave 0..7
    const int l = t & 63;
    const int lm = l & 15, lw = l >> 4;
    // XCD decode: bid&7 = (g + 4b) -> one (b,g) per XCD
    const int bid = blockIdx.x;
    const int g = bid & 3;
    const int b = (bid >> 2) & 1;
    const int within = bid >> 3;
    const int xq = within & 7;
    const int h = g * 4 + (within >> 3);
    const int swz = (lm & 7) << 3;

    const ushort* kbase = QKV + (size_t)(b * SS) * QKVS + 2048 + g * HDIM;
    const ushort* vbase = VT + ((size_t)b * DKV + g * HDIM) * SS;

    const short one_bf = (short)0x3F80;
    const bf16x8 ones = {one_bf, one_bf, one_bf, one_bf, one_bf, one_bf, one_bf, one_bf};

    const int kr0 = t >> 4, ko0 = t & 15;
    const int kr1 = (t + 512) >> 4, ko1 = (t + 512) & 15;
    const int vr0 = t >> 3, vo0 = t & 7;
    const int vr1 = (t + 512) >> 3, vo1 = (t + 512) & 7;

#pragma unroll 1
    for (int phase = 0; phase < 2; ++phase) {
        const int qt = (phase == 0) ? xq : (15 - xq);
        const int q0 = qt * 128;
        const int qw = q0 + w * 16;
        const int q = qw + lm;
        const int ntiles = 2 * qt + 2;
        const int lt = (qw + 15) >> 6;   // last kv-tile this wave needs

        const ushort* ks0 = kbase + (size_t)kr0 * QKVS + ((ko0 ^ (kr0 & 7)) * 8);
        const ushort* ks1 = kbase + (size_t)kr1 * QKVS + ((ko1 ^ (kr1 & 7)) * 8);
        const ushort* vs0 = vbase + (size_t)vr0 * SS + ((vo0 ^ (vr0 & 7)) * 8);
        const ushort* vs1 = vbase + (size_t)vr1 * SS + ((vo1 ^ (vr1 & 7)) * 8);

        bf16x8 qa[4];
        {
            const ushort* qp = QKV + (size_t)(b * SS + qw + lm) * QKVS + h * HDIM + lw * 8;
#pragma unroll
            for (int kk = 0; kk < 4; ++kk)
                qa[kk] = *(const bf16x8*)(qp + kk * 32);
        }

        f32x4 acc[8];
#pragma unroll
        for (int d = 0; d < 8; ++d) acc[d] = (f32x4){0.f, 0.f, 0.f, 0.f};
        f32x4 accl = (f32x4){0.f, 0.f, 0.f, 0.f};
        float m = -INFINITY;
        bf16x8 pa[2] = {};               // P fragments, consumed next tile

        // PV cluster (uses pa + V slot)
        auto DO_PV = [&](int vslot) {
            __builtin_amdgcn_s_setprio(1);
#pragma unroll
            for (int kks = 0; kks < 2; ++kks) {
                accl = __builtin_amdgcn_mfma_f32_16x16x32_bf16(pa[kks], ones, accl, 0, 0, 0);
#pragma unroll
                for (int dcol = 0; dcol < 8; ++dcol) {
                    bf16x8 vb = *(const bf16x8*)&Vs[vslot][(dcol * 16 + lm) * 64 + ((kks * 32 + lw * 8) ^ swz)];
                    acc[dcol] = __builtin_amdgcn_mfma_f32_16x16x32_bf16(pa[kks], vb, acc[dcol], 0, 0, 0);
                }
            }
            __builtin_amdgcn_s_setprio(0);
        };

        // prologue: stage tile 0 (K->Ks[0], V->Vs[0])
        GLOAD_LDS(ks0, &Ks[0][t * 8]);
        ks0 += 64 * QKVS;
        GLOAD_LDS(ks1, &Ks[0][(t + 512) * 8]);
        ks1 += 64 * QKVS;
        GLOAD_LDS(vs0, &Vs[0][t * 8]);
        vs0 += 64;
        GLOAD_LDS(vs1, &Vs[0][(t + 512) * 8]);
        vs1 += 64;
        asm volatile("s_waitcnt vmcnt(0)" ::: "memory");
        __builtin_amdgcn_s_barrier();

        int vprev = 2, vcur = 0, vnext = 1;

#pragma unroll 1
        for (int tile = 0; tile < ntiles; ++tile) {
            const int kv0 = tile * 64;
            const bool more = (tile + 1 < ntiles);
            if (more) {  // stage K(t+1) -> Ks[(t+1)&1], V(t+1) -> Vs[vnext]
                ushort* kd = &Ks[(tile + 1) & 1][0];
                ushort* vd = &Vs[vnext][0];
                GLOAD_LDS(ks0, kd + t * 8);
                ks0 += 64 * QKVS;
                GLOAD_LDS(ks1, kd + (t + 512) * 8);
                ks1 += 64 * QKVS;
                GLOAD_LDS(vs0, vd + t * 8);
                vs0 += 64;
                GLOAD_LDS(vs1, vd + (t + 512) * 8);
                vs1 += 64;
            }

            f32x4 sfT[4];
            const bool active = (tile <= lt);
            if (active) {
                // ---- QK^T(t): S^T = mfma(K, Q) ----
#pragma unroll
                for (int kvb = 0; kvb < 4; ++kvb) sfT[kvb] = (f32x4){0.f, 0.f, 0.f, 0.f};
                __builtin_amdgcn_s_setprio(1);
#pragma unroll
                for (int kvb = 0; kvb < 4; ++kvb)
#pragma unroll
                    for (int kk = 0; kk < 4; ++kk) {
                        bf16x8 kb = *(const bf16x8*)&Ks[tile & 1][(kvb * 16 + lm) * 128 + ((kk * 32 + lw * 8) ^ swz)];
                        sfT[kvb] = __builtin_amdgcn_mfma_f32_16x16x32_bf16(kb, qa[kk], sfT[kvb], 0, 0, 0);
                    }
                __builtin_amdgcn_s_setprio(0);
            }

            // ---- PV(t-1) from pa + Vs[vprev] (in acc BEFORE tile-t rescale) ----
            if (tile >= 1 && tile <= lt + 1) DO_PV(vprev);

            if (active) {
                // ---- softmax(t) -> pa(t) ----
                if (tile == lt) {
#pragma unroll
                    for (int kvb = 0; kvb < 4; ++kvb)
#pragma unroll
                        for (int r = 0; r < 4; ++r) {
                            int kv = kv0 + kvb * 16 + lw * 4 + r;
                            if (kv > q) sfT[kvb][r] = -INFINITY;
                        }
                }
                float rm = fmaxf(fmaxf(sfT[0][0], sfT[0][1]), fmaxf(sfT[0][2], sfT[0][3]));
#pragma unroll
                for (int kvb = 1; kvb < 4; ++kvb)
                    rm = fmaxf(rm, fmaxf(fmaxf(sfT[kvb][0], sfT[kvb][1]),
                                         fmaxf(sfT[kvb][2], sfT[kvb][3])));
                rm = fmaxf(rm, __shfl_xor(rm, 16));
                rm = fmaxf(rm, __shfl_xor(rm, 32));

                bool stable = (rm - m <= THRRAW);
                if (!__all((int)stable)) {
                    float mn = fmaxf(m, rm);
                    float alpha_l = exp2f((m - mn) * CEXP);
                    m = mn;
                    float ar[4];
#pragma unroll
                    for (int r = 0; r < 4; ++r)
                        ar[r] = __shfl(alpha_l, (l & 48) | (lw * 4 + r));
#pragma unroll
                    for (int d = 0; d < 8; ++d) {
                        acc[d][0] *= ar[0];
                        acc[d][1] *= ar[1];
                        acc[d][2] *= ar[2];
                        acc[d][3] *= ar[3];
                    }
                    accl[0] *= ar[0];
                    accl[1] *= ar[1];
                    accl[2] *= ar[2];
                    accl[3] *= ar[3];
                }

                float mC = m * CEXP;
#pragma unroll
                for (int kvb = 0; kvb < 4; ++kvb)
#pragma unroll
                    for (int r = 0; r < 4; ++r) {
                        float pv = exp2f(fmaf(sfT[kvb][r], CEXP, -mC));
                        pa[kvb >> 1][(kvb & 1) * 4 + r] = (short)f2bf(pv);
                    }
            }

            if (more) {
                asm volatile("s_waitcnt vmcnt(0)" ::: "memory");
                __builtin_amdgcn_s_barrier();
            }
            vprev = vcur;
            vcur = vnext;
            vnext = (vnext == 2) ? 0 : vnext + 1;
        }

        // flush PV(lt) if not already flushed in-loop (lt == ntiles-1 case)
        if (lt == ntiles - 1) DO_PV(lt % 3);

        // ---- epilogue ----
        float rinv[4];
#pragma unroll
        for (int r = 0; r < 4; ++r) rinv[r] = 1.f / accl[r];
        ushort* cp = Ctx + (size_t)(b * SS + qw) * DD + h * HDIM;
#pragma unroll
        for (int d = 0; d < 8; ++d)
#pragma unroll
            for (int r = 0; r < 4; ++r)
                cp[(size_t)(lw * 4 + r) * DD + d * 16 + lm] = f2bf(acc[d][r] * rinv[r]);
        __builtin_amdgcn_s_barrier();  // protect LDS before next phase prologue
    }
}

extern "C" void kernel_launch(void* const* d_in, const int* in_sizes, int n_in,
                              void* d_out, int out_size, void* d_ws, size_t ws_size,
                              hipStream_t stream) {
    const float* x  = (const float*)d_in[0];
    const float* Wq = (const float*)d_in[1];
    const float* Wk = (const float*)d_in[2];
    const float* Wv = (const float*)d_in[3];
    const float* Wo = (const float*)d_in[4];
    float* out = (float*)d_out;

    // bf16 workspace (~67 MB)
    ushort* xh    = (ushort*)d_ws;                    // [MS, DD]
    ushort* QKV   = xh + (size_t)MS * DD;             // [MS, QKVS]
    ushort* VTb   = QKV + (size_t)MS * QKVS;          // [BB*DKV, SS]
    ushort* WqkvT = VTb + (size_t)MS * DKV;           // [QKVS, DD]
    ushort* WoT   = WqkvT + (size_t)QKVS * DD;        // [DD, DD]
    ushort* Ch    = xh;                               // ctx bf16 aliases xh

    dim3 blk(256);
    int nx8 = MS * DD / 8;
    cast_bf16<<<(nx8 + 255) / 256, 256, 0, stream>>>(x, xh, nx8);

    // merged Wq/Wk/Wv transpose+cast (z-indexed)
    transpose_cast3<<<dim3(DD / 32, DD / 32, 3), blk, 0, stream>>>(Wq, Wk, Wv, WqkvT);

    // fused QKV GEMM: BM=128, BN=256 -> 12 x 32 = 384 blocks (2-resident/CU)
    gemm8<256, true><<<dim3(QKVS / 256, MS / 128), dim3(512), 0, stream>>>(xh, WqkvT, QKV, MS, QKVS, DD);

    // fused RoPE over Q (heads 0..15) and K (heads 16..19)
    int nrope = MS * 20 * 64;
    rope_bf16<<<(nrope + 255) / 256, 256, 0, stream>>>(QKV, nrope);

    transpose_v<<<dim3(DKV / 32, SS / 32, BB), blk, 0, stream>>>(QKV, VTb);

    // attention: 256 blocks x 512 threads, 2-deep P pipeline
    attn_mfma<<<dim3(256), dim3(512), 0, stream>>>(QKV, VTb, Ch);

    transpose_cast<<<dim3(DD / 32, DD / 32), blk, 0, stream>>>(Wo, WoT, DD, DD);
    // Wo GEMM: BM=128, BN=128 -> 16 x 32 = 512 blocks (exactly 2/CU)
    gemm8<128, false><<<dim3(DD / 128, MS / 128), dim3(512), 0, stream>>>(Ch, WoT, out, MS, DD, DD);
}

// Round 16
// 203.204 us; speedup vs baseline: 1.0498x; 1.0498x over previous
//
#include <hip/hip_runtime.h>
#include <hip/hip_bf16.h>
#include <math.h>

// Problem constants
#define BB 2
#define SS 2048
#define DD 2048
#define HH 16
#define GG 4
#define HDIM 128
#define DKV (GG * HDIM)      // 512
#define MS (BB * SS)         // 4096 rows
#define QKVS 3072            // fused QKV row stride (2048 Q + 512 K + 512 V)

typedef __attribute__((ext_vector_type(8))) short bf16x8;
typedef __attribute__((ext_vector_type(4))) float f32x4;
typedef __attribute__((ext_vector_type(4))) unsigned int u32x4;

__device__ __forceinline__ ushort f2bf(float x) {
    __hip_bfloat16 b = __float2bfloat16(x);
    return *(ushort*)&b;
}
__device__ __forceinline__ float bf2f(ushort u) {
    __hip_bfloat16 b;
    *(ushort*)&b = u;
    return __bfloat162float(b);
}

#define GLOAD_LDS(src, dst)                                                        \
    __builtin_amdgcn_global_load_lds(                                              \
        (const __attribute__((address_space(1))) unsigned int*)(src),              \
        (__attribute__((address_space(3))) unsigned int*)(dst), 16, 0, 0)

#define WAITV(n) asm volatile("s_waitcnt vmcnt(" #n ")" ::: "memory")

// ---------------- fp32 -> bf16 cast, 8 elems/thread ----------------
__global__ void cast_bf16(const float* __restrict__ X, ushort* __restrict__ O, int total8) {
    int idx = blockIdx.x * blockDim.x + threadIdx.x;
    if (idx >= total8) return;
    const float4* p = (const float4*)X + (size_t)idx * 2;
    float4 a = p[0], b = p[1];
    float v[8] = {a.x, a.y, a.z, a.w, b.x, b.y, b.z, b.w};
    ushort r[8];
#pragma unroll
    for (int j = 0; j < 8; ++j) r[j] = f2bf(v[j]);
    *((u32x4*)O + idx) = *(u32x4*)r;
}

// --- merged weight transpose+cast: z=0 Wq, z=1 Wk, z=2 Wv -> WqkvT; z=3 Wo -> WoT
__global__ __launch_bounds__(256) void transpose_cast4(const float* __restrict__ Wq,
                                                       const float* __restrict__ Wk,
                                                       const float* __restrict__ Wv,
                                                       const float* __restrict__ Wo,
                                                       ushort* __restrict__ WqkvT,
                                                       ushort* __restrict__ WoT) {
    __shared__ ushort tile[32][33];
    const int z = blockIdx.z;
    if ((z == 1 || z == 2) && blockIdx.x >= DKV / 32) return;
    const float* W = (z == 0) ? Wq : (z == 1) ? Wk : (z == 2) ? Wv : Wo;
    ushort* WT = (z == 3) ? WoT
                          : WqkvT + ((z == 0) ? (size_t)0
                                              : (z == 1) ? (size_t)DD * DD
                                                         : (size_t)(DD + DKV) * DD);
    const int N = (z == 1 || z == 2) ? DKV : DD;
    const int tx = threadIdx.x & 31, ty = threadIdx.x >> 5;  // 32 x 8
    const int n0 = blockIdx.x * 32, k0 = blockIdx.y * 32;
#pragma unroll
    for (int i = 0; i < 4; ++i)
        tile[ty + i * 8][tx] = f2bf(W[(size_t)(k0 + ty + i * 8) * N + n0 + tx]);
    __syncthreads();
#pragma unroll
    for (int i = 0; i < 4; ++i)
        WT[(size_t)(n0 + ty + i * 8) * DD + k0 + tx] = tile[tx][ty + i * 8];
}

// ---- per-batch V transpose from fused QKV, with PV-slot column permutation ----
// tau: kv = 32a+16m+4w+r  ->  pos = 32a+8w+4m+r
__global__ __launch_bounds__(256) void transpose_v(const ushort* __restrict__ QKV,
                                                   ushort* __restrict__ VT) {
    __shared__ ushort tile[32][33];
    const int tx = threadIdx.x & 31, ty = threadIdx.x >> 5;
    const int d0 = blockIdx.x * 32;
    const int k0 = blockIdx.y * 32;
    const int b = blockIdx.z;
#pragma unroll
    for (int i = 0; i < 4; ++i)
        tile[ty + i * 8][tx] =
            QKV[(size_t)(b * SS + k0 + ty + i * 8) * QKVS + 2560 + d0 + tx];
    __syncthreads();
    const int posl = ((tx & 12) << 1) | ((tx & 16) >> 2) | (tx & 3);
#pragma unroll
    for (int i = 0; i < 4; ++i)
        VT[((size_t)b * DKV + d0 + ty + i * 8) * SS + k0 + posl] = tile[tx][ty + i * 8];
}

// ---------------- bf16 MFMA GEMM v3: BM=128, ring-3, 2 blocks/CU ---------------
template <int BN, bool OUT_BF16>
__global__ __launch_bounds__(512) void gemm8(const ushort* __restrict__ A,
                                             const ushort* __restrict__ BT,
                                             void* __restrict__ Cout,
                                             int M, int N, int K) {
    constexpr int ABUF = 128 * 32;
    constexpr int BBUF = BN * 32;
    constexpr int NWC = BN / 64;
    constexpr int NWM = 8 / NWC;
    constexpr int ROWS = 128 / NWM;
    constexpr int MFR = ROWS / 16;
    __shared__ ushort As[3 * ABUF];
    __shared__ ushort Bs[3 * BBUF];

    const int t = threadIdx.x;
    const int w = t >> 6, l = t & 63;
    const int lm = l & 15, lw = l >> 4;
    const int wr = w / NWC, wc = w % NWC;
    const int nx = gridDim.x;
    const int bid = blockIdx.y * nx + blockIdx.x;
    const int cpx = (nx * gridDim.y) >> 3;
    const int swb = (bid & 7) * cpx + (bid >> 3);
    const int bm = (swb / nx) * 128, bn = (swb % nx) * BN;

    const int NT = K >> 5;
    const int swzc = (lw ^ ((lm >> 1) & 3)) * 8;

    const int ar0 = t >> 2, ac0 = (t & 3) ^ ((ar0 >> 1) & 3);
    const ushort* a0 = A + (size_t)(bm + ar0) * K + ac0 * 8;
    const int br0 = t >> 2, bc0 = (t & 3) ^ ((br0 >> 1) & 3);
    const ushort* b0 = BT + (size_t)(bn + br0) * K + bc0 * 8;
    const int br1 = (t + 512) >> 2, bc1 = ((t + 512) & 3) ^ ((br1 >> 1) & 3);
    const ushort* b1 = BT + (size_t)(bn + br1) * K + bc1 * 8;  // BN==256 only

    auto STAGE = [&](int slot) {
        GLOAD_LDS(a0, &As[slot * ABUF + t * 8]);
        a0 += 32;
        GLOAD_LDS(b0, &Bs[slot * BBUF + t * 8]);
        b0 += 32;
        if constexpr (BN == 256) {
            GLOAD_LDS(b1, &Bs[slot * BBUF + (t + 512) * 8]);
            b1 += 32;
        }
    };

    f32x4 acc[MFR][4];
#pragma unroll
    for (int m = 0; m < MFR; ++m)
#pragma unroll
        for (int n = 0; n < 4; ++n) acc[m][n] = (f32x4){0.f, 0.f, 0.f, 0.f};

    STAGE(0);
    STAGE(1);
    int cs = 0, ps = 2;

#pragma unroll 1
    for (int kt = 0; kt < NT; ++kt) {
        if (kt + 1 < NT) {
            if constexpr (BN == 256) WAITV(3); else WAITV(2);
        } else {
            WAITV(0);
        }
        __builtin_amdgcn_s_barrier();
        if (kt + 2 < NT) STAGE(ps);

        const ushort* Ab = &As[cs * ABUF];
        const ushort* Bb = &Bs[cs * BBUF];
        bf16x8 bfr[4], af[MFR];
#pragma unroll
        for (int n = 0; n < 4; ++n)
            bfr[n] = *(const bf16x8*)&Bb[(wc * 64 + n * 16 + lm) * 32 + swzc];
#pragma unroll
        for (int i = 0; i < MFR; ++i)
            af[i] = *(const bf16x8*)&Ab[(wr * ROWS + i * 16 + lm) * 32 + swzc];
        __builtin_amdgcn_s_setprio(1);
#pragma unroll
        for (int i = 0; i < MFR; ++i)
#pragma unroll
            for (int n = 0; n < 4; ++n)
                acc[i][n] = __builtin_amdgcn_mfma_f32_16x16x32_bf16(af[i], bfr[n], acc[i][n], 0, 0, 0);
        __builtin_amdgcn_s_setprio(0);

        cs = (cs == 2) ? 0 : cs + 1;
        ps = (ps == 2) ? 0 : ps + 1;
    }

#pragma unroll
    for (int m = 0; m < MFR; ++m)
#pragma unroll
        for (int n = 0; n < 4; ++n)
#pragma unroll
            for (int r = 0; r < 4; ++r) {
                int row = bm + wr * ROWS + m * 16 + lw * 4 + r;
                int col = bn + wc * 64 + n * 16 + lm;
                if (OUT_BF16)
                    ((ushort*)Cout)[(size_t)row * N + col] = f2bf(acc[m][n][r]);
                else
                    ((float*)Cout)[(size_t)row * N + col] = acc[m][n][r];
            }
}

// ------- RoPE in-place on bf16, vectorized: 8 (i, i+64) pairs per thread -------
// idx -> (row, hh 0..19, oct 0..7). Loads/stores 16B at base and base+128B.
__global__ void rope_bf16v(ushort* __restrict__ X, int total) {
    int idx = blockIdx.x * blockDim.x + threadIdx.x;
    if (idx >= total) return;
    int oct = idx & 7;
    int hh = (idx >> 3) % 20;
    int row = idx / (8 * 20);
    int s = row & (SS - 1);
    int colOff = (hh < 16) ? hh * HDIM : 2048 + (hh - 16) * HDIM;
    size_t base = (size_t)row * QKVS + colOff + oct * 8;
    u32x4 lo = *(u32x4*)&X[base];
    u32x4 hi = *(u32x4*)&X[base + 64];
    ushort* lp = (ushort*)&lo;
    ushort* hp = (ushort*)&hi;
    ushort ro[8], rh[8];
#pragma unroll
    for (int j = 0; j < 8; ++j) {
        int i = oct * 8 + j;
        float inv = exp2f((float)i * -0.2076205059304601f);  // 10000^(-2i/128)
        float ang = (float)s * inv;
        float c, sn;
        __sincosf(ang, &sn, &c);
        float x1 = bf2f(lp[j]), x2 = bf2f(hp[j]);
        ro[j] = f2bf(x1 * c - x2 * sn);
        rh[j] = f2bf(x2 * c + x1 * sn);
    }
    *(u32x4*)&X[base] = *(u32x4*)ro;
    *(u32x4*)&X[base + 64] = *(u32x4*)rh;
}

// ---------------- MFMA flash attention v9 (round-11, 72 us measured) ----------
// 256 blocks x 8 waves, q-tile 128, paired phases {xq, 15-xq}. K,V both
// double-buffered (64 KB); ONE vmcnt(0)+barrier per tile (prefetch issued at
// tile top has the whole tile to land). Swapped QK^T + tau-permuted V.
#define SCL 0.08838834764831845f          // 1/sqrt(128)
#define CEXP 0.1275296340545927f          // SCL * log2(e)
#define THRRAW 90.50966799187809f         // 8 / SCL

__global__ __launch_bounds__(512) void attn_mfma(const ushort* __restrict__ QKV,
                                                 const ushort* __restrict__ VT,
                                                 ushort* __restrict__ Ctx) {
    __shared__ ushort Ks[2][64 * 128];  // 32 KB
    __shared__ ushort Vs[2][128 * 64];  // 32 KB
    const int t = threadIdx.x;          // 0..511
    const int w = t >> 6;               // wave 0..7
    const int l = t & 63;
    const int lm = l & 15, lw = l >> 4;
    // XCD decode: bid&7 = (g + 4b) -> one (b,g) per XCD
    const int bid = blockIdx.x;
    const int g = bid & 3;
    const int b = (bid >> 2) & 1;
    const int within = bid >> 3;
    const int xq = within & 7;
    const int h = g * 4 + (within >> 3);
    const int swz = (lm & 7) << 3;

    const ushort* kbase = QKV + (size_t)(b * SS) * QKVS + 2048 + g * HDIM;
    const ushort* vbase = VT + ((size_t)b * DKV + g * HDIM) * SS;

    const short one_bf = (short)0x3F80;
    const bf16x8 ones = {one_bf, one_bf, one_bf, one_bf, one_bf, one_bf, one_bf, one_bf};

    const int kr0 = t >> 4, ko0 = t & 15;
    const int kr1 = (t + 512) >> 4, ko1 = (t + 512) & 15;
    const int vr0 = t >> 3, vo0 = t & 7;
    const int vr1 = (t + 512) >> 3, vo1 = (t + 512) & 7;
    ushort* kd0a = &Ks[0][t * 8];
    ushort* kd0b = &Ks[1][t * 8];
    ushort* kd1a = &Ks[0][(t + 512) * 8];
    ushort* kd1b = &Ks[1][(t + 512) * 8];
    ushort* vd0a = &Vs[0][t * 8];
    ushort* vd0b = &Vs[1][t * 8];
    ushort* vd1a = &Vs[0][(t + 512) * 8];
    ushort* vd1b = &Vs[1][(t + 512) * 8];

#pragma unroll 1
    for (int phase = 0; phase < 2; ++phase) {
        const int qt = (phase == 0) ? xq : (15 - xq);
        const int q0 = qt * 128;
        const int qw = q0 + w * 16;
        const int q = qw + lm;
        const int ntiles = 2 * qt + 2;
        const int lt = (qw + 15) >> 6;

        const ushort* ks0 = kbase + (size_t)kr0 * QKVS + ((ko0 ^ (kr0 & 7)) * 8);
        const ushort* ks1 = kbase + (size_t)kr1 * QKVS + ((ko1 ^ (kr1 & 7)) * 8);
        const ushort* vs0 = vbase + (size_t)vr0 * SS + ((vo0 ^ (vr0 & 7)) * 8);
        const ushort* vs1 = vbase + (size_t)vr1 * SS + ((vo1 ^ (vr1 & 7)) * 8);

        bf16x8 qa[4];
        {
            const ushort* qp = QKV + (size_t)(b * SS + qw + lm) * QKVS + h * HDIM + lw * 8;
#pragma unroll
            for (int kk = 0; kk < 4; ++kk)
                qa[kk] = *(const bf16x8*)(qp + kk * 32);
        }

        f32x4 acc[8];
#pragma unroll
        for (int d = 0; d < 8; ++d) acc[d] = (f32x4){0.f, 0.f, 0.f, 0.f};
        f32x4 accl = (f32x4){0.f, 0.f, 0.f, 0.f};
        float m = -INFINITY;

        GLOAD_LDS(ks0, kd0a);
        GLOAD_LDS(ks1, kd1a);
        ks0 += 64 * QKVS;
        ks1 += 64 * QKVS;
        GLOAD_LDS(vs0, vd0a);
        GLOAD_LDS(vs1, vd1a);
        vs0 += 64;
        vs1 += 64;
        asm volatile("s_waitcnt vmcnt(0)" ::: "memory");
        __builtin_amdgcn_s_barrier();

#pragma unroll 1
        for (int tile = 0; tile < ntiles; ++tile) {
            const int cur = tile & 1;
            const int kv0 = tile * 64;
            const bool more = (tile + 1 < ntiles);
            if (more) {
                GLOAD_LDS(ks0, cur ? kd0a : kd0b);
                GLOAD_LDS(ks1, cur ? kd1a : kd1b);
                ks0 += 64 * QKVS;
                ks1 += 64 * QKVS;
                GLOAD_LDS(vs0, cur ? vd0a : vd0b);
                GLOAD_LDS(vs1, cur ? vd1a : vd1b);
                vs0 += 64;
                vs1 += 64;
            }

            if (tile <= lt) {
                f32x4 sfT[4];
#pragma unroll
                for (int kvb = 0; kvb < 4; ++kvb) sfT[kvb] = (f32x4){0.f, 0.f, 0.f, 0.f};
                __builtin_amdgcn_s_setprio(1);
#pragma unroll
                for (int kvb = 0; kvb < 4; ++kvb)
#pragma unroll
                    for (int kk = 0; kk < 4; ++kk) {
                        bf16x8 kb = *(const bf16x8*)&Ks[cur][(kvb * 16 + lm) * 128 + ((kk * 32 + lw * 8) ^ swz)];
                        sfT[kvb] = __builtin_amdgcn_mfma_f32_16x16x32_bf16(kb, qa[kk], sfT[kvb], 0, 0, 0);
                    }
                __builtin_amdgcn_s_setprio(0);

                if (tile == lt) {
#pragma unroll
                    for (int kvb = 0; kvb < 4; ++kvb)
#pragma unroll
                        for (int r = 0; r < 4; ++r) {
                            int kv = kv0 + kvb * 16 + lw * 4 + r;
                            if (kv > q) sfT[kvb][r] = -INFINITY;
                        }
                }

                float rm = fmaxf(fmaxf(sfT[0][0], sfT[0][1]), fmaxf(sfT[0][2], sfT[0][3]));
#pragma unroll
                for (int kvb = 1; kvb < 4; ++kvb)
                    rm = fmaxf(rm, fmaxf(fmaxf(sfT[kvb][0], sfT[kvb][1]),
                                         fmaxf(sfT[kvb][2], sfT[kvb][3])));
                rm = fmaxf(rm, __shfl_xor(rm, 16));
                rm = fmaxf(rm, __shfl_xor(rm, 32));

                bool stable = (rm - m <= THRRAW);
                if (!__all((int)stable)) {
                    float mn = fmaxf(m, rm);
                    float alpha_l = exp2f((m - mn) * CEXP);
                    m = mn;
                    float ar[4];
#pragma unroll
                    for (int r = 0; r < 4; ++r)
                        ar[r] = __shfl(alpha_l, (l & 48) | (lw * 4 + r));
#pragma unroll
                    for (int d = 0; d < 8; ++d) {
                        acc[d][0] *= ar[0];
                        acc[d][1] *= ar[1];
                        acc[d][2] *= ar[2];
                        acc[d][3] *= ar[3];
                    }
                    accl[0] *= ar[0];
                    accl[1] *= ar[1];
                    accl[2] *= ar[2];
                    accl[3] *= ar[3];
                }

                bf16x8 pa[2];
                float mC = m * CEXP;
#pragma unroll
                for (int kvb = 0; kvb < 4; ++kvb)
#pragma unroll
                    for (int r = 0; r < 4; ++r) {
                        float pv = exp2f(fmaf(sfT[kvb][r], CEXP, -mC));
                        pa[kvb >> 1][(kvb & 1) * 4 + r] = (short)f2bf(pv);
                    }

                __builtin_amdgcn_s_setprio(1);
#pragma unroll
                for (int kks = 0; kks < 2; ++kks) {
                    accl = __builtin_amdgcn_mfma_f32_16x16x32_bf16(pa[kks], ones, accl, 0, 0, 0);
#pragma unroll
                    for (int dcol = 0; dcol < 8; ++dcol) {
                        bf16x8 vb = *(const bf16x8*)&Vs[cur][(dcol * 16 + lm) * 64 + ((kks * 32 + lw * 8) ^ swz)];
                        acc[dcol] = __builtin_amdgcn_mfma_f32_16x16x32_bf16(pa[kks], vb, acc[dcol], 0, 0, 0);
                    }
                }
                __builtin_amdgcn_s_setprio(0);
            }

            if (more) {
                asm volatile("s_waitcnt vmcnt(0)" ::: "memory");
                __builtin_amdgcn_s_barrier();
            }
        }

        float rinv[4];
#pragma unroll
        for (int r = 0; r < 4; ++r) rinv[r] = 1.f / accl[r];
        ushort* cp = Ctx + (size_t)(b * SS + qw) * DD + h * HDIM;
#pragma unroll
        for (int d = 0; d < 8; ++d)
#pragma unroll
            for (int r = 0; r < 4; ++r)
                cp[(size_t)(lw * 4 + r) * DD + d * 16 + lm] = f2bf(acc[d][r] * rinv[r]);
        __builtin_amdgcn_s_barrier();
    }
}

extern "C" void kernel_launch(void* const* d_in, const int* in_sizes, int n_in,
                              void* d_out, int out_size, void* d_ws, size_t ws_size,
                              hipStream_t stream) {
    const float* x  = (const float*)d_in[0];
    const float* Wq = (const float*)d_in[1];
    const float* Wk = (const float*)d_in[2];
    const float* Wv = (const float*)d_in[3];
    const float* Wo = (const float*)d_in[4];
    float* out = (float*)d_out;

    // bf16 workspace (~67 MB)
    ushort* xh    = (ushort*)d_ws;                    // [MS, DD]
    ushort* QKV   = xh + (size_t)MS * DD;             // [MS, QKVS]
    ushort* VTb   = QKV + (size_t)MS * QKVS;          // [BB*DKV, SS]
    ushort* WqkvT = VTb + (size_t)MS * DKV;           // [QKVS, DD]
    ushort* WoT   = WqkvT + (size_t)QKVS * DD;        // [DD, DD]
    ushort* Ch    = xh;                               // ctx bf16 aliases xh

    dim3 blk(256);
    int nx8 = MS * DD / 8;
    cast_bf16<<<(nx8 + 255) / 256, 256, 0, stream>>>(x, xh, nx8);

    // merged Wq/Wk/Wv/Wo transpose+cast (z-indexed, one launch)
    transpose_cast4<<<dim3(DD / 32, DD / 32, 4), blk, 0, stream>>>(Wq, Wk, Wv, Wo, WqkvT, WoT);

    // fused QKV GEMM: BM=128, BN=256 -> 12 x 32 = 384 blocks (2-resident/CU)
    gemm8<256, true><<<dim3(QKVS / 256, MS / 128), dim3(512), 0, stream>>>(xh, WqkvT, QKV, MS, QKVS, DD);

    // vectorized RoPE over Q (heads 0..15) and K (heads 16..19): 8 pairs/thread
    int nrope = MS * 20 * 8;
    rope_bf16v<<<(nrope + 255) / 256, 256, 0, stream>>>(QKV, nrope);

    transpose_v<<<dim3(DKV / 32, SS / 32, BB), blk, 0, stream>>>(QKV, VTb);

    // attention: 256 blocks x 512 threads (round-11 v9, 72 us)
    attn_mfma<<<dim3(256), dim3(512), 0, stream>>>(QKV, VTb, Ch);

    // Wo GEMM: BM=128, BN=128 -> 16 x 32 = 512 blocks (exactly 2/CU)
    gemm8<128, false><<<dim3(DD / 128, MS / 128), dim3(512), 0, stream>>>(Ch, WoT, out, MS, DD, DD);
}

// Round 17
// 196.885 us; speedup vs baseline: 1.0835x; 1.0321x over previous
//
#include <hip/hip_runtime.h>
#include <hip/hip_bf16.h>
#include <math.h>

// Problem constants
#define BB 2
#define SS 2048
#define DD 2048
#define HH 16
#define GG 4
#define HDIM 128
#define DKV (GG * HDIM)      // 512
#define MS (BB * SS)         // 4096 rows
#define QKVS 3072            // fused QKV row stride (2048 Q + 512 K + 512 V)

typedef __attribute__((ext_vector_type(8))) short bf16x8;
typedef __attribute__((ext_vector_type(4))) float f32x4;
typedef __attribute__((ext_vector_type(4))) unsigned int u32x4;

#if __has_builtin(__builtin_amdgcn_exp2f)
#define EXP2F __builtin_amdgcn_exp2f
#else
#define EXP2F exp2f
#endif

__device__ __forceinline__ ushort f2bf(float x) {
    __hip_bfloat16 b = __float2bfloat16(x);
    return *(ushort*)&b;
}
__device__ __forceinline__ float bf2f(ushort u) {
    __hip_bfloat16 b;
    *(ushort*)&b = u;
    return __bfloat162float(b);
}

#define GLOAD_LDS(src, dst)                                                        \
    __builtin_amdgcn_global_load_lds(                                              \
        (const __attribute__((address_space(1))) unsigned int*)(src),              \
        (__attribute__((address_space(3))) unsigned int*)(dst), 16, 0, 0)

#define WAITV(n) asm volatile("s_waitcnt vmcnt(" #n ")" ::: "memory")

// ---------------- fp32 -> bf16 cast, 8 elems/thread ----------------
__global__ void cast_bf16(const float* __restrict__ X, ushort* __restrict__ O, int total8) {
    int idx = blockIdx.x * blockDim.x + threadIdx.x;
    if (idx >= total8) return;
    const float4* p = (const float4*)X + (size_t)idx * 2;
    float4 a = p[0], b = p[1];
    float v[8] = {a.x, a.y, a.z, a.w, b.x, b.y, b.z, b.w};
    ushort r[8];
#pragma unroll
    for (int j = 0; j < 8; ++j) r[j] = f2bf(v[j]);
    *((u32x4*)O + idx) = *(u32x4*)r;
}

// --- merged weight transpose+cast: z=0 Wq, z=1 Wk, z=2 Wv -> WqkvT; z=3 Wo -> WoT
__global__ __launch_bounds__(256) void transpose_cast4(const float* __restrict__ Wq,
                                                       const float* __restrict__ Wk,
                                                       const float* __restrict__ Wv,
                                                       const float* __restrict__ Wo,
                                                       ushort* __restrict__ WqkvT,
                                                       ushort* __restrict__ WoT) {
    __shared__ ushort tile[32][33];
    const int z = blockIdx.z;
    if ((z == 1 || z == 2) && blockIdx.x >= DKV / 32) return;
    const float* W = (z == 0) ? Wq : (z == 1) ? Wk : (z == 2) ? Wv : Wo;
    ushort* WT = (z == 3) ? WoT
                          : WqkvT + ((z == 0) ? (size_t)0
                                              : (z == 1) ? (size_t)DD * DD
                                                         : (size_t)(DD + DKV) * DD);
    const int N = (z == 1 || z == 2) ? DKV : DD;
    const int tx = threadIdx.x & 31, ty = threadIdx.x >> 5;  // 32 x 8
    const int n0 = blockIdx.x * 32, k0 = blockIdx.y * 32;
#pragma unroll
    for (int i = 0; i < 4; ++i)
        tile[ty + i * 8][tx] = f2bf(W[(size_t)(k0 + ty + i * 8) * N + n0 + tx]);
    __syncthreads();
#pragma unroll
    for (int i = 0; i < 4; ++i)
        WT[(size_t)(n0 + ty + i * 8) * DD + k0 + tx] = tile[tx][ty + i * 8];
}

// ---- per-batch V transpose from fused QKV, with PV-slot column permutation ----
// tau: kv = 32a+16m+4w+r  ->  pos = 32a+8w+4m+r
__global__ __launch_bounds__(256) void transpose_v(const ushort* __restrict__ QKV,
                                                   ushort* __restrict__ VT) {
    __shared__ ushort tile[32][33];
    const int tx = threadIdx.x & 31, ty = threadIdx.x >> 5;
    const int d0 = blockIdx.x * 32;
    const int k0 = blockIdx.y * 32;
    const int b = blockIdx.z;
#pragma unroll
    for (int i = 0; i < 4; ++i)
        tile[ty + i * 8][tx] =
            QKV[(size_t)(b * SS + k0 + ty + i * 8) * QKVS + 2560 + d0 + tx];
    __syncthreads();
    const int posl = ((tx & 12) << 1) | ((tx & 16) >> 2) | (tx & 3);
#pragma unroll
    for (int i = 0; i < 4; ++i)
        VT[((size_t)b * DKV + d0 + ty + i * 8) * SS + k0 + posl] = tile[tx][ty + i * 8];
}

// ---------------- bf16 MFMA GEMM v3: BM=128, ring-3, 2 blocks/CU ---------------
template <int BN, bool OUT_BF16>
__global__ __launch_bounds__(512) void gemm8(const ushort* __restrict__ A,
                                             const ushort* __restrict__ BT,
                                             void* __restrict__ Cout,
                                             int M, int N, int K) {
    constexpr int ABUF = 128 * 32;
    constexpr int BBUF = BN * 32;
    constexpr int NWC = BN / 64;
    constexpr int NWM = 8 / NWC;
    constexpr int ROWS = 128 / NWM;
    constexpr int MFR = ROWS / 16;
    __shared__ ushort As[3 * ABUF];
    __shared__ ushort Bs[3 * BBUF];

    const int t = threadIdx.x;
    const int w = t >> 6, l = t & 63;
    const int lm = l & 15, lw = l >> 4;
    const int wr = w / NWC, wc = w % NWC;
    const int nx = gridDim.x;
    const int bid = blockIdx.y * nx + blockIdx.x;
    const int cpx = (nx * gridDim.y) >> 3;
    const int swb = (bid & 7) * cpx + (bid >> 3);
    const int bm = (swb / nx) * 128, bn = (swb % nx) * BN;

    const int NT = K >> 5;
    const int swzc = (lw ^ ((lm >> 1) & 3)) * 8;

    const int ar0 = t >> 2, ac0 = (t & 3) ^ ((ar0 >> 1) & 3);
    const ushort* a0 = A + (size_t)(bm + ar0) * K + ac0 * 8;
    const int br0 = t >> 2, bc0 = (t & 3) ^ ((br0 >> 1) & 3);
    const ushort* b0 = BT + (size_t)(bn + br0) * K + bc0 * 8;
    const int br1 = (t + 512) >> 2, bc1 = ((t + 512) & 3) ^ ((br1 >> 1) & 3);
    const ushort* b1 = BT + (size_t)(bn + br1) * K + bc1 * 8;  // BN==256 only

    auto STAGE = [&](int slot) {
        GLOAD_LDS(a0, &As[slot * ABUF + t * 8]);
        a0 += 32;
        GLOAD_LDS(b0, &Bs[slot * BBUF + t * 8]);
        b0 += 32;
        if constexpr (BN == 256) {
            GLOAD_LDS(b1, &Bs[slot * BBUF + (t + 512) * 8]);
            b1 += 32;
        }
    };

    f32x4 acc[MFR][4];
#pragma unroll
    for (int m = 0; m < MFR; ++m)
#pragma unroll
        for (int n = 0; n < 4; ++n) acc[m][n] = (f32x4){0.f, 0.f, 0.f, 0.f};

    STAGE(0);
    STAGE(1);
    int cs = 0, ps = 2;

#pragma unroll 1
    for (int kt = 0; kt < NT; ++kt) {
        if (kt + 1 < NT) {
            if constexpr (BN == 256) WAITV(3); else WAITV(2);
        } else {
            WAITV(0);
        }
        __builtin_amdgcn_s_barrier();
        if (kt + 2 < NT) STAGE(ps);

        const ushort* Ab = &As[cs * ABUF];
        const ushort* Bb = &Bs[cs * BBUF];
        bf16x8 bfr[4], af[MFR];
#pragma unroll
        for (int n = 0; n < 4; ++n)
            bfr[n] = *(const bf16x8*)&Bb[(wc * 64 + n * 16 + lm) * 32 + swzc];
#pragma unroll
        for (int i = 0; i < MFR; ++i)
            af[i] = *(const bf16x8*)&Ab[(wr * ROWS + i * 16 + lm) * 32 + swzc];
        __builtin_amdgcn_s_setprio(1);
#pragma unroll
        for (int i = 0; i < MFR; ++i)
#pragma unroll
            for (int n = 0; n < 4; ++n)
                acc[i][n] = __builtin_amdgcn_mfma_f32_16x16x32_bf16(af[i], bfr[n], acc[i][n], 0, 0, 0);
        __builtin_amdgcn_s_setprio(0);

        cs = (cs == 2) ? 0 : cs + 1;
        ps = (ps == 2) ? 0 : ps + 1;
    }

#pragma unroll
    for (int m = 0; m < MFR; ++m)
#pragma unroll
        for (int n = 0; n < 4; ++n)
#pragma unroll
            for (int r = 0; r < 4; ++r) {
                int row = bm + wr * ROWS + m * 16 + lw * 4 + r;
                int col = bn + wc * 64 + n * 16 + lm;
                if (OUT_BF16)
                    ((ushort*)Cout)[(size_t)row * N + col] = f2bf(acc[m][n][r]);
                else
                    ((float*)Cout)[(size_t)row * N + col] = acc[m][n][r];
            }
}

// ------- RoPE in-place on bf16, vectorized: 8 (i, i+64) pairs per thread -------
__global__ void rope_bf16v(ushort* __restrict__ X, int total) {
    int idx = blockIdx.x * blockDim.x + threadIdx.x;
    if (idx >= total) return;
    int oct = idx & 7;
    int hh = (idx >> 3) % 20;
    int row = idx / (8 * 20);
    int s = row & (SS - 1);
    int colOff = (hh < 16) ? hh * HDIM : 2048 + (hh - 16) * HDIM;
    size_t base = (size_t)row * QKVS + colOff + oct * 8;
    u32x4 lo = *(u32x4*)&X[base];
    u32x4 hi = *(u32x4*)&X[base + 64];
    ushort* lp = (ushort*)&lo;
    ushort* hp = (ushort*)&hi;
    ushort ro[8], rh[8];
#pragma unroll
    for (int j = 0; j < 8; ++j) {
        int i = oct * 8 + j;
        float inv = exp2f((float)i * -0.2076205059304601f);  // 10000^(-2i/128)
        float ang = (float)s * inv;
        float c, sn;
        __sincosf(ang, &sn, &c);
        float x1 = bf2f(lp[j]), x2 = bf2f(hp[j]);
        ro[j] = f2bf(x1 * c - x2 * sn);
        rh[j] = f2bf(x2 * c + x1 * sn);
    }
    *(u32x4*)&X[base] = *(u32x4*)ro;
    *(u32x4*)&X[base + 64] = *(u32x4*)rh;
}

// ---------------- MFMA flash attention v14: kv-tile 128 (half the convoys) ----
// 256 blocks x 8 waves, q-tile 128, paired phases {xq, 15-xq}. K,V double-
// buffered 128-kv tiles (128 KB LDS); 17 convoys/block (vs 34). With kv=128,
// lt == ntiles-1 for every wave: no per-wave tile skip; mask only on the
// final tile. Swapped QK^T + tau-permuted V (verified conventions).
#define SCL 0.08838834764831845f          // 1/sqrt(128)
#define CEXP 0.1275296340545927f          // SCL * log2(e)
#define THRRAW 90.50966799187809f         // 8 / SCL

__global__ __launch_bounds__(512) void attn_mfma(const ushort* __restrict__ QKV,
                                                 const ushort* __restrict__ VT,
                                                 ushort* __restrict__ Ctx) {
    __shared__ ushort Ks[2][128 * 128];  // 64 KB
    __shared__ ushort Vs[2][128 * 128];  // 64 KB
    const int t = threadIdx.x;           // 0..511
    const int w = t >> 6;                // wave 0..7
    const int l = t & 63;
    const int lm = l & 15, lw = l >> 4;
    // XCD decode: bid&7 = (g + 4b) -> one (b,g) per XCD
    const int bid = blockIdx.x;
    const int g = bid & 3;
    const int b = (bid >> 2) & 1;
    const int within = bid >> 3;
    const int xq = within & 7;
    const int h = g * 4 + (within >> 3);
    const int swz = (lm & 7) << 3;

    const ushort* kbase = QKV + (size_t)(b * SS) * QKVS + 2048 + g * HDIM;
    const ushort* vbase = VT + ((size_t)b * DKV + g * HDIM) * SS;

    const short one_bf = (short)0x3F80;
    const bf16x8 ones = {one_bf, one_bf, one_bf, one_bf, one_bf, one_bf, one_bf, one_bf};

    // staging chunk geometry: K tile 128x128 = 2048 16B-chunks; V same.
    // chunk c = t + it*512 (it 0..3): row c>>4, col-chunk c&15, swizzled source.
    int krr[4], koo[4];
#pragma unroll
    for (int it = 0; it < 4; ++it) {
        int c = t + it * 512;
        krr[it] = c >> 4;
        koo[it] = (c & 15) ^ (krr[it] & 7);
    }

#pragma unroll 1
    for (int phase = 0; phase < 2; ++phase) {
        const int qt = (phase == 0) ? xq : (15 - xq);
        const int q0 = qt * 128;
        const int qw = q0 + w * 16;
        const int q = qw + lm;
        const int ntiles = qt + 1;       // kv-tiles of 128; lt == ntiles-1 for all waves

        const ushort* ks[4];
        const ushort* vs[4];
#pragma unroll
        for (int it = 0; it < 4; ++it) {
            ks[it] = kbase + (size_t)krr[it] * QKVS + koo[it] * 8;
            vs[it] = vbase + (size_t)krr[it] * SS + koo[it] * 8;
        }

        bf16x8 qa[4];
        {
            const ushort* qp = QKV + (size_t)(b * SS + qw + lm) * QKVS + h * HDIM + lw * 8;
#pragma unroll
            for (int kk = 0; kk < 4; ++kk)
                qa[kk] = *(const bf16x8*)(qp + kk * 32);
        }

        f32x4 acc[8];
#pragma unroll
        for (int d = 0; d < 8; ++d) acc[d] = (f32x4){0.f, 0.f, 0.f, 0.f};
        f32x4 accl = (f32x4){0.f, 0.f, 0.f, 0.f};
        float m = -INFINITY;

        // prologue: stage tile 0 into buffer 0 (4 K + 4 V chunks per thread)
#pragma unroll
        for (int it = 0; it < 4; ++it) {
            GLOAD_LDS(ks[it], &Ks[0][(t + it * 512) * 8]);
            ks[it] += 128 * QKVS;
            GLOAD_LDS(vs[it], &Vs[0][(t + it * 512) * 8]);
            vs[it] += 128;
        }
        asm volatile("s_waitcnt vmcnt(0)" ::: "memory");
        __builtin_amdgcn_s_barrier();

#pragma unroll 1
        for (int tile = 0; tile < ntiles; ++tile) {
            const int cur = tile & 1;
            const int kv0 = tile * 128;
            const bool more = (tile + 1 < ntiles);
            if (more) {  // issue next 128-kv tile into other buffer
                ushort* kd = &Ks[cur ^ 1][0];
                ushort* vd = &Vs[cur ^ 1][0];
#pragma unroll
                for (int it = 0; it < 4; ++it) {
                    GLOAD_LDS(ks[it], kd + (t + it * 512) * 8);
                    ks[it] += 128 * QKVS;
                    GLOAD_LDS(vs[it], vd + (t + it * 512) * 8);
                    vs[it] += 128;
                }
            }

            // ---- S^T = mfma(K, Q): lane holds S[q=lm][kv=kv0+16kvb+4lw+r] ----
            f32x4 sfT[8];
#pragma unroll
            for (int kvb = 0; kvb < 8; ++kvb) sfT[kvb] = (f32x4){0.f, 0.f, 0.f, 0.f};
            __builtin_amdgcn_s_setprio(1);
#pragma unroll
            for (int kvb = 0; kvb < 8; ++kvb)
#pragma unroll
                for (int kk = 0; kk < 4; ++kk) {
                    bf16x8 kb = *(const bf16x8*)&Ks[cur][(kvb * 16 + lm) * 128 + ((kk * 32 + lw * 8) ^ swz)];
                    sfT[kvb] = __builtin_amdgcn_mfma_f32_16x16x32_bf16(kb, qa[kk], sfT[kvb], 0, 0, 0);
                }
            __builtin_amdgcn_s_setprio(0);

            // ---- mask (final tile only; uniform across waves) ----
            if (tile == ntiles - 1) {
#pragma unroll
                for (int kvb = 0; kvb < 8; ++kvb)
#pragma unroll
                    for (int r = 0; r < 4; ++r) {
                        int kv = kv0 + kvb * 16 + lw * 4 + r;
                        if (kv > q) sfT[kvb][r] = -INFINITY;
                    }
            }

            // ---- in-lane row max + cross-lw reduce (2 shfl) ----
            float rm = fmaxf(fmaxf(sfT[0][0], sfT[0][1]), fmaxf(sfT[0][2], sfT[0][3]));
#pragma unroll
            for (int kvb = 1; kvb < 8; ++kvb)
                rm = fmaxf(rm, fmaxf(fmaxf(sfT[kvb][0], sfT[kvb][1]),
                                     fmaxf(sfT[kvb][2], sfT[kvb][3])));
            rm = fmaxf(rm, __shfl_xor(rm, 16));
            rm = fmaxf(rm, __shfl_xor(rm, 32));

            // ---- defer-max rescale ----
            bool stable = (rm - m <= THRRAW);
            if (!__all((int)stable)) {
                float mn = fmaxf(m, rm);
                float alpha_l = EXP2F((m - mn) * CEXP);
                m = mn;
                float ar[4];
#pragma unroll
                for (int r = 0; r < 4; ++r)
                    ar[r] = __shfl(alpha_l, (l & 48) | (lw * 4 + r));
#pragma unroll
                for (int d = 0; d < 8; ++d) {
                    acc[d][0] *= ar[0];
                    acc[d][1] *= ar[1];
                    acc[d][2] *= ar[2];
                    acc[d][3] *= ar[3];
                }
                accl[0] *= ar[0];
                accl[1] *= ar[1];
                accl[2] *= ar[2];
                accl[3] *= ar[3];
            }

            // ---- P = exp2((s-m)*CEXP), packed straight into A-fragments ----
            bf16x8 pa[4];
            float mC = m * CEXP;
#pragma unroll
            for (int kvb = 0; kvb < 8; ++kvb)
#pragma unroll
                for (int r = 0; r < 4; ++r) {
                    float pv = EXP2F(fmaf(sfT[kvb][r], CEXP, -mC));
                    pa[kvb >> 1][(kvb & 1) * 4 + r] = (short)f2bf(pv);
                }

            // ---- PV + l via ones-MFMA (V columns tau-permuted) ----
            __builtin_amdgcn_s_setprio(1);
#pragma unroll
            for (int kks = 0; kks < 4; ++kks) {
                accl = __builtin_amdgcn_mfma_f32_16x16x32_bf16(pa[kks], ones, accl, 0, 0, 0);
#pragma unroll
                for (int dcol = 0; dcol < 8; ++dcol) {
                    bf16x8 vb = *(const bf16x8*)&Vs[cur][(dcol * 16 + lm) * 128 + ((kks * 32 + lw * 8) ^ swz)];
                    acc[dcol] = __builtin_amdgcn_mfma_f32_16x16x32_bf16(pa[kks], vb, acc[dcol], 0, 0, 0);
                }
            }
            __builtin_amdgcn_s_setprio(0);

            if (more) {
                asm volatile("s_waitcnt vmcnt(0)" ::: "memory");
                __builtin_amdgcn_s_barrier();
            }
        }

        // ---- epilogue: O[q=qw+lw*4+r][d=dcol*16+lm] = acc/l ----
        float rinv[4];
#pragma unroll
        for (int r = 0; r < 4; ++r) rinv[r] = 1.f / accl[r];
        ushort* cp = Ctx + (size_t)(b * SS + qw) * DD + h * HDIM;
#pragma unroll
        for (int d = 0; d < 8; ++d)
#pragma unroll
            for (int r = 0; r < 4; ++r)
                cp[(size_t)(lw * 4 + r) * DD + d * 16 + lm] = f2bf(acc[d][r] * rinv[r]);
        __builtin_amdgcn_s_barrier();  // protect LDS before next phase prologue
    }
}

extern "C" void kernel_launch(void* const* d_in, const int* in_sizes, int n_in,
                              void* d_out, int out_size, void* d_ws, size_t ws_size,
                              hipStream_t stream) {
    const float* x  = (const float*)d_in[0];
    const float* Wq = (const float*)d_in[1];
    const float* Wk = (const float*)d_in[2];
    const float* Wv = (const float*)d_in[3];
    const float* Wo = (const float*)d_in[4];
    float* out = (float*)d_out;

    // bf16 workspace (~67 MB)
    ushort* xh    = (ushort*)d_ws;                    // [MS, DD]
    ushort* QKV   = xh + (size_t)MS * DD;             // [MS, QKVS]
    ushort* VTb   = QKV + (size_t)MS * QKVS;          // [BB*DKV, SS]
    ushort* WqkvT = VTb + (size_t)MS * DKV;           // [QKVS, DD]
    ushort* WoT   = WqkvT + (size_t)QKVS * DD;        // [DD, DD]
    ushort* Ch    = xh;                               // ctx bf16 aliases xh

    dim3 blk(256);
    int nx8 = MS * DD / 8;
    cast_bf16<<<(nx8 + 255) / 256, 256, 0, stream>>>(x, xh, nx8);

    // merged Wq/Wk/Wv/Wo transpose+cast (z-indexed, one launch)
    transpose_cast4<<<dim3(DD / 32, DD / 32, 4), blk, 0, stream>>>(Wq, Wk, Wv, Wo, WqkvT, WoT);

    // fused QKV GEMM: BM=128, BN=256 -> 12 x 32 = 384 blocks (2-resident/CU)
    gemm8<256, true><<<dim3(QKVS / 256, MS / 128), dim3(512), 0, stream>>>(xh, WqkvT, QKV, MS, QKVS, DD);

    // vectorized RoPE over Q (heads 0..15) and K (heads 16..19): 8 pairs/thread
    int nrope = MS * 20 * 8;
    rope_bf16v<<<(nrope + 255) / 256, 256, 0, stream>>>(QKV, nrope);

    transpose_v<<<dim3(DKV / 32, SS / 32, BB), blk, 0, stream>>>(QKV, VTb);

    // attention: 256 blocks x 512 threads, kv-tile 128 (17 convoys/block)
    attn_mfma<<<dim3(256), dim3(512), 0, stream>>>(QKV, VTb, Ch);

    // Wo GEMM: BM=128, BN=128 -> 16 x 32 = 512 blocks (exactly 2/CU)
    gemm8<128, false><<<dim3(DD / 128, MS / 128), dim3(512), 0, stream>>>(Ch, WoT, out, MS, DD, DD);
}